// Round 8
// baseline (199.151 us; speedup 1.0000x reference)
//
#include <hip/hip_runtime.h>

#define N_NODES 50000
#define N_EDGES 800000
#define DIM 128
#define NT 4
#define NR 6
#define NH 8
#define NBLK_SCAN ((N_NODES + 255) / 256)   // 196
#define NTILE_ROW 3129                      // ceil((N + 4*15)/16)
#define NPAD_MAX (NTILE_ROW * 16)           // 50064
#define CHUNK 8
#define NCHUNK ((NTILE_ROW + CHUNK - 1) / CHUNK)   // 392
#define GEMM_BLOCKS (NCHUNK * 6)                   // 2352

#define XCVT_N (N_NODES * DIM / 4)          // 1,600,000 float4s
#define WT_N   (NT * 3 * DIM * DIM)         // 196,608 elems
#define WCB_N  (24 * 32)                    // 768 table entries
#define PREP_TOTAL (XCVT_N + WT_N + WCB_N)
#define PREP_BLOCKS ((PREP_TOTAL + 255) / 256)
#define HIST_BLOCKS (N_EDGES / 256)                     // 3125
#define MID_PREP_BASE NBLK_SCAN
#define MID_HIST_BASE (NBLK_SCAN + PREP_BLOCKS)
#define MID_BLOCKS (MID_HIST_BASE + HIST_BLOCKS)

typedef __attribute__((ext_vector_type(8))) short bf16x8;
typedef __attribute__((ext_vector_type(4))) float f32x4;

__device__ __forceinline__ unsigned short f2bf(float f) {
    unsigned int u = __float_as_uint(f);
    return (unsigned short)((u + 0x7fffu + ((u >> 16) & 1u)) >> 16);
}
__device__ __forceinline__ float blo(unsigned int u) { return __uint_as_float(u << 16); }
__device__ __forceinline__ float bhi(unsigned int u) { return __uint_as_float(u & 0xffff0000u); }

__device__ __forceinline__ int sign_index(int s) {
    // es = where((s < -1)|(s==0), -2, clip(s,-1,1)); idx: -1->0, 1->1, else->2
    if (s < -1 || s == 0) return 2;
    return (s == -1) ? 0 : 1;
}

// ---------------- node type histogram + buffer inits (fused memsets) ----------------
__global__ __launch_bounds__(256) void k_typehist(const int* __restrict__ ntype,
                                                  int* __restrict__ bhist,
                                                  int* __restrict__ cnt,
                                                  int* __restrict__ opad) {
    __shared__ int h[NT];
    if (threadIdx.x < NT) h[threadIdx.x] = 0;
    __syncthreads();
    int n = blockIdx.x * 256 + threadIdx.x;
    if (n < N_NODES) { atomicAdd(&h[ntype[n]], 1); cnt[n] = 0; }
    if (n < NPAD_MAX) opad[n] = -1;
    __syncthreads();
    if (threadIdx.x < NT) bhist[blockIdx.x * NT + threadIdx.x] = h[threadIdx.x];
}

// scan block histograms (type-major) -> per-(block,type) bases with x16-padded type bases
__global__ __launch_bounds__(1024) void k_typescan(const int* __restrict__ bhist,
                                                   int* __restrict__ bbase,
                                                   int* __restrict__ pb_g) {
    __shared__ int s[1024];
    __shared__ int pb[NT + 1];
    int tid = threadIdx.x;
    int t = tid / NBLK_SCAN;
    int b = tid - t * NBLK_SCAN;
    int v = (tid < NT * NBLK_SCAN) ? bhist[b * NT + t] : 0;
    s[tid] = v;
    __syncthreads();
    for (int d = 1; d < 1024; d <<= 1) {
        int add = (tid >= d) ? s[tid - d] : 0;
        __syncthreads();
        s[tid] += add;
        __syncthreads();
    }
    if (tid == 0) {
        int acc = 0;
        for (int tt = 0; tt < NT; ++tt) {
            pb[tt] = acc;
            int tot = s[(tt + 1) * NBLK_SCAN - 1] - (tt ? s[tt * NBLK_SCAN - 1] : 0);
            acc += ((tot + 15) >> 4) << 4;
        }
        pb[NT] = acc;
    }
    __syncthreads();
    if (tid < NT * NBLK_SCAN) {
        int excl = s[tid] - v;
        int base_t = t ? s[t * NBLK_SCAN - 1] : 0;
        bbase[b * NT + t] = pb[t] + (excl - base_t);
    }
    if (tid <= NT) pb_g[tid] = pb[tid];
}

// ---------------- fused middle stage: scatter2 | prep | hist2 ----------------
__global__ __launch_bounds__(256) void k_mid(
    const int* __restrict__ ntype, const int* __restrict__ bbase, int* __restrict__ order_pad,
    const float* __restrict__ x,
    const float* __restrict__ Wq, const float* __restrict__ Wk, const float* __restrict__ Wv,
    const float* __restrict__ rel_q, const float* __restrict__ rel_k,
    const float* __restrict__ rel_v,
    const float* __restrict__ skn, const float* __restrict__ svn,
    unsigned short* __restrict__ xb, unsigned short* __restrict__ Wt,
    float4* __restrict__ wcbK, float4* __restrict__ wcbV,
    const int* __restrict__ ei, int* __restrict__ cnt, int* __restrict__ posw)
{
    int blk = blockIdx.x;
    if (blk < NBLK_SCAN) {
        // ---- scatter nodes into type-bucketed padded order ----
        __shared__ int cur[NT];
        if (threadIdx.x < NT) cur[threadIdx.x] = bbase[blk * NT + threadIdx.x];
        __syncthreads();
        int n = blk * 256 + threadIdx.x;
        if (n < N_NODES) {
            int t = ntype[n];
            int pos = atomicAdd(&cur[t], 1);   // LDS atomic
            order_pad[pos] = n;
        }
        return;
    }
    if (blk < MID_HIST_BASE) {
        int i = (blk - MID_PREP_BASE) * 256 + threadIdx.x;
        if (i < XCVT_N) {
            float4 v = ((const float4*)x)[i];
            ushort4 o;
            o.x = f2bf(v.x); o.y = f2bf(v.y); o.z = f2bf(v.z); o.w = f2bf(v.w);
            ((ushort4*)xb)[i] = o;
        } else if (i < XCVT_N + WT_N) {
            int j = i - XCVT_N;            // Wt[ts][out][in], ts = t*3+sel
            int in = j & 127;
            int b2 = j >> 7;
            int out = b2 & 127;
            int ts = b2 >> 7;
            int sel = ts % 3, t = ts / 3;
            const float* W = sel == 0 ? Wq : (sel == 1 ? Wk : Wv);
            Wt[j] = f2bf(W[((size_t)t * DIM + in) * DIM + out]);
        } else if (i < PREP_TOTAL) {
            // f32 weight tables: wcbK[cmb][p] = wqk for elems 4p..4p+3, wcbV = wv
            int j = i - XCVT_N - WT_N;     // cmb*32 + p
            int p = j & 31;
            int cmb = j >> 5;
            int et = cmb & 7, sidx = cmb >> 3;
            if (et < NR) {
                int h = p >> 2;
                float wk[4], wv[4];
                #pragma unroll
                for (int q = 0; q < 4; ++q) {
                    int o = 4 * p + q;
                    int rb = (et * NH + h) * 16 + (o & 15);
                    float sgk = sidx == 0 ? -1.f : (sidx == 1 ? 1.f : skn[o]);
                    float sgv = sidx == 0 ? -1.f : (sidx == 1 ? 1.f : svn[o]);
                    wk[q] = rel_q[rb] * rel_k[rb] * sgk * 0.25f;
                    wv[q] = rel_v[rb] * sgv;
                }
                wcbK[cmb * 32 + p] = make_float4(wk[0], wk[1], wk[2], wk[3]);
                wcbV[cmb * 32 + p] = make_float4(wv[0], wv[1], wv[2], wv[3]);
            }
        }
        return;
    }
    // ---- edge histogram with position-within return ----
    int e = (blk - MID_HIST_BASE) * 256 + threadIdx.x;
    if (e < N_EDGES) posw[e] = atomicAdd(&cnt[ei[N_EDGES + e]], 1);
}

// ---------------- MFMA projection (B-frag register-resident over row chunks) + scan1 ----------------
// KVu layout per node: 64 groups x {k0,k1,v0,v1} ushorts (512B/row)
__global__ __launch_bounds__(256) void k_projm(
    const unsigned short* __restrict__ xb, const unsigned short* __restrict__ Wt,
    const int* __restrict__ order_pad, const int* __restrict__ pb_g,
    const float* __restrict__ bq, const float* __restrict__ bk, const float* __restrict__ bv,
    float* __restrict__ Qf, unsigned short* __restrict__ KVu,
    const int* __restrict__ cnt, int* __restrict__ offs, int* __restrict__ bsum)
{
    int b = blockIdx.x;
    if (b >= GEMM_BLOCKS) {
        // ---- scan1: block-local exclusive scan of edge counts ----
        int sb = b - GEMM_BLOCKS;
        __shared__ int s[256];
        int i = sb * 256 + threadIdx.x;
        int v = (i < N_NODES) ? cnt[i] : 0;
        s[threadIdx.x] = v;
        __syncthreads();
        for (int d = 1; d < 256; d <<= 1) {
            int add = (threadIdx.x >= d) ? s[threadIdx.x - d] : 0;
            __syncthreads();
            s[threadIdx.x] += add;
            __syncthreads();
        }
        if (i < N_NODES) offs[i] = s[threadIdx.x] - v;
        if (threadIdx.x == 255) bsum[sb] = s[255];
        return;
    }
    int chunk = b / 6, g = b % 6;
    int wave = threadIdx.x >> 6, lane = threadIdx.x & 63;
    int ocol = g * 64 + wave * 16 + (lane & 15);
    int sel = ocol >> 7, wcol = ocol & 127;
    int ko = (lane >> 4) * 8;
    const float* bias_p = sel == 0 ? bq : (sel == 1 ? bk : bv);
    int cur_t = -1;
    bf16x8 bfr[4];
    float bias = 0.f;
    int tile0 = chunk * CHUNK;
    int tmax = pb_g[NT];
    #pragma unroll 1
    for (int tt = 0; tt < CHUNK; ++tt) {
        int row0 = (tile0 + tt) * 16;
        if (row0 >= tmax) break;
        int t = (row0 >= pb_g[3]) ? 3 : (row0 >= pb_g[2]) ? 2 : (row0 >= pb_g[1]) ? 1 : 0;
        if (t != cur_t) {
            cur_t = t;
            const unsigned short* wrow = Wt + ((size_t)(t * 3 + sel) * DIM + wcol) * DIM;
            #pragma unroll
            for (int kt = 0; kt < 4; ++kt) bfr[kt] = *(const bf16x8*)(wrow + kt * 32 + ko);
            bias = bias_p[t * DIM + wcol];
        }
        int arow = row0 + (lane & 15);
        int nidA = order_pad[arow];
        const unsigned short* xrow = xb + (size_t)(nidA < 0 ? 0 : nidA) * DIM;
        f32x4 acc = {0.f, 0.f, 0.f, 0.f};
        #pragma unroll
        for (int kt = 0; kt < 4; ++kt) {
            bf16x8 a = *(const bf16x8*)(xrow + kt * 32 + ko);
            acc = __builtin_amdgcn_mfma_f32_16x16x32_bf16(a, bfr[kt], acc, 0, 0, 0);
        }
        #pragma unroll
        for (int r = 0; r < 4; ++r) {
            int drow = row0 + (lane >> 4) * 4 + r;
            int nid = order_pad[drow];
            if (nid < 0) continue;
            float v = acc[r] + bias;
            if (sel == 0) Qf[(size_t)nid * DIM + wcol] = v;
            else KVu[(size_t)nid * 256 + (wcol >> 1) * 4 + (wcol & 1) + (sel == 2 ? 2 : 0)] = f2bf(v);
        }
    }
}

// scan of per-block sums; offs[N] boundary pre-compensated for bofs
__global__ __launch_bounds__(256) void k_scan2(const int* __restrict__ bsum,
                                               int* __restrict__ bofs, int* __restrict__ offs) {
    __shared__ int s[256];
    int t = threadIdx.x;
    int v = (t < NBLK_SCAN) ? bsum[t] : 0;
    s[t] = v;
    __syncthreads();
    for (int d = 1; d < 256; d <<= 1) {
        int add = (t >= d) ? s[t - d] : 0;
        __syncthreads();
        s[t] += add;
        __syncthreads();
    }
    if (t < NBLK_SCAN) {
        int b = s[t] - v;
        bofs[t] = b;
        if (t == NBLK_SCAN - 1) offs[N_NODES] = N_EDGES - b;  // so offs[N]+bofs[N>>8]==E
    }
}

// emit edge records {src|cmb<<16, phi} into dst-sorted slots — no atomics
__global__ void k_emit(const int* __restrict__ ei, const int* __restrict__ etype,
                       const int* __restrict__ esign, const float* __restrict__ edist,
                       const float* __restrict__ dalpha, const float* __restrict__ dtau,
                       const int* __restrict__ offs, const int* __restrict__ bofs,
                       const int* __restrict__ posw, int2* __restrict__ edata) {
    int e = blockIdx.x * blockDim.x + threadIdx.x;
    if (e >= N_EDGES) return;
    int dst = ei[N_EDGES + e];
    int pos = offs[dst] + bofs[dst >> 8] + posw[e];
    int cmb = sign_index(esign[e]) * 8 + etype[e];
    float phi = dalpha[0] * __expf(-edist[e] / (dtau[0] + 1e-9f));
    edata[pos] = make_int2(ei[e] | (cmb << 16), __float_as_int(phi));
}

// ---------------- fused attention + aggregation + skip + LN ----------------
// 256 threads = 4 waves; one wave per node. Each 32-lane HALF owns one edge;
// lane holds a 4-element quad. Depth-2 software pipeline on edata/KV/weight loads.
__global__ __launch_bounds__(256) void k_attn(
    const float4* __restrict__ Qf4, const uint4* __restrict__ KV,
    const float4* __restrict__ WK, const float4* __restrict__ WV,
    const float* __restrict__ x, const int* __restrict__ ntype,
    const int* __restrict__ offs, const int* __restrict__ bofs,
    const int2* __restrict__ edata,
    const float* __restrict__ rbias, const float* __restrict__ skip,
    const float* __restrict__ gmm, const float* __restrict__ bta,
    float* __restrict__ out)
{
    __shared__ float rb_s[NR * NH];
    if (threadIdx.x < NR * NH) rb_s[threadIdx.x] = rbias[threadIdx.x];
    __syncthreads();
    const int wave = threadIdx.x >> 6, lane = threadIdx.x & 63;
    const int n = blockIdx.x * 4 + wave;
    const int p = lane & 31;          // position quad index (elems 4p..4p+3)
    const int hi = lane >> 5;         // which edge of the pair this half owns
    const int h = p >> 2;             // head
    const int beg = offs[n] + bofs[n >> 8];
    const int end = offs[n + 1] + bofs[(n + 1) >> 8];

    const float4 q4 = Qf4[(size_t)n * 32 + p];

    float Z = 0.f, a0 = 0.f, a1 = 0.f, a2 = 0.f, a3 = 0.f;

    // scores bounded; exp without max-shift is safe in f32 (softmax shift-invariant)
    auto PROC = [&](int2 r, uint4 kv, float4 wk, float4 wv) {
        float pp = (q4.x * wk.x) * blo(kv.x);
        pp = fmaf(q4.y * wk.y, bhi(kv.x), pp);
        pp = fmaf(q4.z * wk.z, blo(kv.z), pp);
        pp = fmaf(q4.w * wk.w, bhi(kv.z), pp);
        pp += __shfl_xor(pp, 1, 4);
        pp += __shfl_xor(pp, 2, 4);
        unsigned cmb = ((unsigned)r.x) >> 16;
        float ex = __expf(pp + rb_s[(cmb & 7) * NH + h] + __int_as_float(r.y));
        Z += ex;
        a0 = fmaf(blo(kv.y) * wv.x, ex, a0);
        a1 = fmaf(bhi(kv.y) * wv.y, ex, a1);
        a2 = fmaf(blo(kv.w) * wv.z, ex, a2);
        a3 = fmaf(bhi(kv.w) * wv.w, ex, a3);
    };

    int rem = end - beg;
    int j = beg;
    if (rem >= 4) {
        int2 r0 = edata[j + hi], r1 = edata[j + 2 + hi];
        uint4  kv0 = KV[(size_t)(r0.x & 0xffff) * 32 + p];
        float4 wk0 = WK[(((unsigned)r0.x) >> 16) * 32 + p];
        float4 wv0 = WV[(((unsigned)r0.x) >> 16) * 32 + p];
        uint4  kv1 = KV[(size_t)(r1.x & 0xffff) * 32 + p];
        float4 wk1 = WK[(((unsigned)r1.x) >> 16) * 32 + p];
        float4 wv1 = WV[(((unsigned)r1.x) >> 16) * 32 + p];
        while (rem >= 8) {
            int2 n0 = edata[j + 4 + hi], n1 = edata[j + 6 + hi];
            uint4  nkv0 = KV[(size_t)(n0.x & 0xffff) * 32 + p];
            float4 nwk0 = WK[(((unsigned)n0.x) >> 16) * 32 + p];
            float4 nwv0 = WV[(((unsigned)n0.x) >> 16) * 32 + p];
            uint4  nkv1 = KV[(size_t)(n1.x & 0xffff) * 32 + p];
            float4 nwk1 = WK[(((unsigned)n1.x) >> 16) * 32 + p];
            float4 nwv1 = WV[(((unsigned)n1.x) >> 16) * 32 + p];
            PROC(r0, kv0, wk0, wv0);
            PROC(r1, kv1, wk1, wv1);
            r0 = n0; kv0 = nkv0; wk0 = nwk0; wv0 = nwv0;
            r1 = n1; kv1 = nkv1; wk1 = nwk1; wv1 = nwv1;
            j += 4; rem -= 4;
        }
        PROC(r0, kv0, wk0, wv0);
        PROC(r1, kv1, wk1, wv1);
        j += 4; rem -= 4;
    }
    while (rem >= 2) {
        int2 r = edata[j + hi];
        uint4  kv = KV[(size_t)(r.x & 0xffff) * 32 + p];
        float4 wk = WK[(((unsigned)r.x) >> 16) * 32 + p];
        float4 wv = WV[(((unsigned)r.x) >> 16) * 32 + p];
        PROC(r, kv, wk, wv);
        j += 2; rem -= 2;
    }
    if (rem) {
        // single leftover edge: both halves compute it; gate the hi half to zero
        int2 r = edata[j];
        uint4  kv = KV[(size_t)(r.x & 0xffff) * 32 + p];
        float4 wk = WK[(((unsigned)r.x) >> 16) * 32 + p];
        float4 wv = WV[(((unsigned)r.x) >> 16) * 32 + p];
        float pp = (q4.x * wk.x) * blo(kv.x);
        pp = fmaf(q4.y * wk.y, bhi(kv.x), pp);
        pp = fmaf(q4.z * wk.z, blo(kv.z), pp);
        pp = fmaf(q4.w * wk.w, bhi(kv.z), pp);
        pp += __shfl_xor(pp, 1, 4);
        pp += __shfl_xor(pp, 2, 4);
        unsigned cmb = ((unsigned)r.x) >> 16;
        float ex = __expf(pp + rb_s[(cmb & 7) * NH + h] + __int_as_float(r.y));
        ex = hi ? 0.f : ex;
        Z += ex;
        a0 = fmaf(blo(kv.y) * wv.x, ex, a0);
        a1 = fmaf(bhi(kv.y) * wv.y, ex, a1);
        a2 = fmaf(blo(kv.w) * wv.z, ex, a2);
        a3 = fmaf(bhi(kv.w) * wv.w, ex, a3);
    }

    // merge the two halves (lanes l and l+32 hold the same positions)
    Z  += __shfl_xor(Z, 32, 64);
    a0 += __shfl_xor(a0, 32, 64);
    a1 += __shfl_xor(a1, 32, 64);
    a2 += __shfl_xor(a2, 32, 64);
    a3 += __shfl_xor(a3, 32, 64);

    float rz = 1.f / (Z + 1e-9f);
    int t = ntype[n];
    float alpha = 1.f / (1.f + __expf(-skip[t]));
    float4 x4 = ((const float4*)x)[(size_t)n * 32 + p];
    float m0 = fmaf(alpha, a0 * rz - x4.x, x4.x);
    float m1 = fmaf(alpha, a1 * rz - x4.y, x4.y);
    float m2 = fmaf(alpha, a2 * rz - x4.z, x4.z);
    float m3 = fmaf(alpha, a3 * rz - x4.w, x4.w);

    float s = (m0 + m1) + (m2 + m3);
    float s2 = fmaf(m0, m0, m1 * m1) + fmaf(m2, m2, m3 * m3);
    #pragma unroll
    for (int d = 32; d >= 1; d >>= 1) {
        s += __shfl_xor(s, d, 64);
        s2 += __shfl_xor(s2, d, 64);
    }
    // both halves duplicated -> divide by 2*DIM
    float mu = s * (1.f / (2 * DIM));
    float var = s2 * (1.f / (2 * DIM)) - mu * mu;
    float rstd = rsqrtf(var + 1e-5f);
    if (hi == 0) {
        float4 g4 = ((const float4*)gmm)[t * 32 + p];
        float4 b4 = ((const float4*)bta)[t * 32 + p];
        float4 o4;
        o4.x = (m0 - mu) * rstd * g4.x + b4.x;
        o4.y = (m1 - mu) * rstd * g4.y + b4.y;
        o4.z = (m2 - mu) * rstd * g4.z + b4.z;
        o4.w = (m3 - mu) * rstd * g4.w + b4.w;
        ((float4*)out)[(size_t)n * 32 + p] = o4;
    }
}

extern "C" void kernel_launch(void* const* d_in, const int* in_sizes, int n_in,
                              void* d_out, int out_size, void* d_ws, size_t ws_size,
                              hipStream_t stream) {
    const float* x      = (const float*)d_in[0];
    const int*   ntype  = (const int*)d_in[1];
    const int*   ei     = (const int*)d_in[2];
    const int*   etype  = (const int*)d_in[3];
    const int*   esign  = (const int*)d_in[4];
    const float* edist  = (const float*)d_in[5];
    const float* Wq     = (const float*)d_in[6];
    const float* bq     = (const float*)d_in[7];
    const float* Wk     = (const float*)d_in[8];
    const float* bk     = (const float*)d_in[9];
    const float* Wv     = (const float*)d_in[10];
    const float* bv     = (const float*)d_in[11];
    const float* rel_q  = (const float*)d_in[12];
    const float* rel_k  = (const float*)d_in[13];
    const float* rel_v  = (const float*)d_in[14];
    const float* skn    = (const float*)d_in[15];
    const float* svn    = (const float*)d_in[16];
    const float* rbias  = (const float*)d_in[17];
    const float* dalpha = (const float*)d_in[18];
    const float* dtau   = (const float*)d_in[19];
    const float* skip   = (const float*)d_in[20];
    const float* gmm    = (const float*)d_in[21];
    const float* bta    = (const float*)d_in[22];
    float* out = (float*)d_out;

    char* ws = (char*)d_ws;
    float*          Qf     = (float*)         (ws + 0);          // 25.6 MB
    unsigned short* KVu    = (unsigned short*)(ws + 25600000);   // 25.6 MB interleaved K/V
    unsigned short* xb     = (unsigned short*)(ws + 51200000);   // 12.8 MB
    unsigned short* Wt     = (unsigned short*)(ws + 64000000);   // 393 KB
    float4*         wcbK   = (float4*)        (ws + 64500000);   // 12.3 KB
    float4*         wcbV   = (float4*)        (ws + 64520000);   // 12.3 KB
    int*            cnt    = (int*)           (ws + 64600000);   // N
    int*            offs   = (int*)           (ws + 64900000);   // N+1
    int*            bsum   = (int*)           (ws + 65200000);   // 256
    int*            bofs   = (int*)           (ws + 65210000);   // 256
    int*            posw   = (int*)           (ws + 65300000);   // E = 3.2 MB
    int2*           edata  = (int2*)          (ws + 68600000);   // E*8 = 6.4 MB
    int*            opad   = (int*)           (ws + 75000000);   // NPAD_MAX
    int*            bhist  = (int*)           (ws + 75300000);   // 196*4
    int*            bbase  = (int*)           (ws + 75310000);   // 196*4
    int*            pb     = (int*)           (ws + 75320000);   // 5

    // 1. type histogram + zero cnt + init opad (fused memsets)
    k_typehist <<<NBLK_SCAN, 256, 0, stream>>>(ntype, bhist, cnt, opad);
    // 2. type-bucket scan (padded to x16)
    k_typescan <<<1, 1024, 0, stream>>>(bhist, bbase, pb);
    // 3. fused: node scatter | prep (x->bf16, W^T->bf16, f32 weight tables) | edge histogram
    k_mid <<<MID_BLOCKS, 256, 0, stream>>>(ntype, bbase, opad,
                                           x, Wq, Wk, Wv, rel_q, rel_k, rel_v, skn, svn,
                                           xb, Wt, wcbK, wcbV,
                                           ei, cnt, posw);
    // 4. MFMA projection (B-resident over row chunks) + scan1 tail blocks
    k_projm <<<GEMM_BLOCKS + NBLK_SCAN, 256, 0, stream>>>(xb, Wt, opad, pb, bq, bk, bv,
                                                          Qf, KVu, cnt, offs, bsum);
    // 5. block-sum scan
    k_scan2 <<<1, 256, 0, stream>>>(bsum, bofs, offs);
    // 6. emit dst-sorted edge records
    k_emit <<<HIST_BLOCKS, 256, 0, stream>>>(ei, etype, esign, edist, dalpha, dtau,
                                             offs, bofs, posw, edata);
    // 7. fused attention + aggregation + skip + LayerNorm
    k_attn <<<N_NODES / 4, 256, 0, stream>>>((const float4*)Qf, (const uint4*)KVu,
                                             (const float4*)wcbK, (const float4*)wcbV,
                                             x, ntype, offs, bofs,
                                             edata, rbias, skip, gmm, bta, out);
}

// Round 9
// 175.322 us; speedup vs baseline: 1.1359x; 1.1359x over previous
//
#include <hip/hip_runtime.h>

#define N_NODES 50000
#define N_EDGES 800000
#define DIM 128
#define NT 4
#define NR 6
#define NH 8
#define NBLK_SCAN ((N_NODES + 255) / 256)   // 196 (type-hist blocks)
#define NBLK2 ((N_NODES + 1023) / 1024)     // 49  (edge-count scan blocks)
#define NTILE_ROW 3129                      // ceil((N + 4*15)/16)
#define NPAD_MAX (NTILE_ROW * 16)           // 50064

#define XCVT_N (N_NODES * DIM / 4)          // 1,600,000 float4s
#define WT_N   (NT * 3 * DIM * DIM)         // 196,608 elems
#define WCB_N  (24 * 32)                    // 768 uint4 entries
#define PREP_TOTAL (XCVT_N + WT_N + WCB_N)
#define PREP_BLOCKS ((PREP_TOTAL + 255) / 256)
#define HIST_BLOCKS (N_EDGES / 256)                     // 3125
#define A_PREP_BASE NBLK_SCAN
#define A_HIST_BASE (NBLK_SCAN + PREP_BLOCKS)
#define A_BLOCKS (A_HIST_BASE + HIST_BLOCKS)

typedef __attribute__((ext_vector_type(8))) short bf16x8;
typedef __attribute__((ext_vector_type(4))) float f32x4;

__device__ __forceinline__ unsigned short f2bf(float f) {
    unsigned int u = __float_as_uint(f);
    return (unsigned short)((u + 0x7fffu + ((u >> 16) & 1u)) >> 16);
}
__device__ __forceinline__ float blo(unsigned int u) { return __uint_as_float(u << 16); }
__device__ __forceinline__ float bhi(unsigned int u) { return __uint_as_float(u & 0xffff0000u); }

__device__ __forceinline__ int sign_index(int s) {
    // es = where((s < -1)|(s==0), -2, clip(s,-1,1)); idx: -1->0, 1->1, else->2
    if (s < -1 || s == 0) return 2;
    return (s == -1) ? 0 : 1;
}

// ============ A: typehist | prep | hist2 (all mutually independent) ============
__global__ __launch_bounds__(256) void k_A(
    const int* __restrict__ ntype, int* __restrict__ bhist, int* __restrict__ opad,
    const float* __restrict__ x,
    const float* __restrict__ Wq, const float* __restrict__ Wk, const float* __restrict__ Wv,
    const float* __restrict__ rel_q, const float* __restrict__ rel_k,
    const float* __restrict__ rel_v,
    const float* __restrict__ skn, const float* __restrict__ svn,
    unsigned short* __restrict__ xb, unsigned short* __restrict__ Wt,
    uint4* __restrict__ wcb,
    const int* __restrict__ ei, int* __restrict__ cnt, int* __restrict__ posw)
{
    int blk = blockIdx.x;
    if (blk < NBLK_SCAN) {
        // ---- node-type histogram + opad init ----
        __shared__ int h[NT];
        if (threadIdx.x < NT) h[threadIdx.x] = 0;
        __syncthreads();
        int n = blk * 256 + threadIdx.x;
        if (n < N_NODES) atomicAdd(&h[ntype[n]], 1);
        if (n < NPAD_MAX) opad[n] = -1;
        __syncthreads();
        if (threadIdx.x < NT) bhist[blk * NT + threadIdx.x] = h[threadIdx.x];
        return;
    }
    if (blk < A_HIST_BASE) {
        // ---- prep: x->bf16 | W->bf16 transposed | packed bf16 weight table ----
        int i = (blk - A_PREP_BASE) * 256 + threadIdx.x;
        if (i < XCVT_N) {
            float4 v = ((const float4*)x)[i];
            ushort4 o;
            o.x = f2bf(v.x); o.y = f2bf(v.y); o.z = f2bf(v.z); o.w = f2bf(v.w);
            ((ushort4*)xb)[i] = o;
        } else if (i < XCVT_N + WT_N) {
            int j = i - XCVT_N;            // Wt[ts][out][in], ts = t*3+sel
            int in = j & 127;
            int b2 = j >> 7;
            int out = b2 & 127;
            int ts = b2 >> 7;
            int sel = ts % 3, t = ts / 3;
            const float* W = sel == 0 ? Wq : (sel == 1 ? Wk : Wv);
            Wt[j] = f2bf(W[((size_t)t * DIM + in) * DIM + out]);
        } else if (i < PREP_TOTAL) {
            // wcb[cmb][p] = {wk(4p),wk(4p+1) | wv(4p),wv(4p+1) | wk(4p+2),wk(4p+3) | wv(4p+2),wv(4p+3)}
            int j = i - XCVT_N - WT_N;     // cmb*32 + p
            int p = j & 31;
            int cmb = j >> 5;
            int et = cmb & 7, sidx = cmb >> 3;
            if (et < NR) {
                int h2 = p >> 2;
                float wk[4], wv[4];
                #pragma unroll
                for (int q = 0; q < 4; ++q) {
                    int o = 4 * p + q;
                    int rb = (et * NH + h2) * 16 + (o & 15);
                    float sgk = sidx == 0 ? -1.f : (sidx == 1 ? 1.f : skn[o]);
                    float sgv = sidx == 0 ? -1.f : (sidx == 1 ? 1.f : svn[o]);
                    wk[q] = rel_q[rb] * rel_k[rb] * sgk * 0.25f;
                    wv[q] = rel_v[rb] * sgv;
                }
                uint4 u;
                u.x = (unsigned)f2bf(wk[0]) | ((unsigned)f2bf(wk[1]) << 16);
                u.y = (unsigned)f2bf(wv[0]) | ((unsigned)f2bf(wv[1]) << 16);
                u.z = (unsigned)f2bf(wk[2]) | ((unsigned)f2bf(wk[3]) << 16);
                u.w = (unsigned)f2bf(wv[2]) | ((unsigned)f2bf(wv[3]) << 16);
                wcb[cmb * 32 + p] = u;
            }
        }
        return;
    }
    // ---- edge histogram with position-within return (cnt pre-zeroed by memset) ----
    int e = (blk - A_HIST_BASE) * 256 + threadIdx.x;
    if (e < N_EDGES) posw[e] = atomicAdd(&cnt[ei[N_EDGES + e]], 1);
}

// ============ B: typescan (block 0) | scan1 (blocks 1..NBLK2) ============
__global__ __launch_bounds__(1024) void k_B(
    const int* __restrict__ bhist, int* __restrict__ bbase, int* __restrict__ pb_g,
    const int* __restrict__ cnt, int* __restrict__ offs, int* __restrict__ bsum)
{
    int tid = threadIdx.x;
    if (blockIdx.x == 0) {
        // ---- scan block histograms (type-major) -> per-(block,type) bases, padded x16 ----
        __shared__ int s[1024];
        __shared__ int pb[NT + 1];
        int t = tid / NBLK_SCAN;
        int b = tid - t * NBLK_SCAN;
        int v = (tid < NT * NBLK_SCAN) ? bhist[b * NT + t] : 0;
        s[tid] = v;
        __syncthreads();
        for (int d = 1; d < 1024; d <<= 1) {
            int add = (tid >= d) ? s[tid - d] : 0;
            __syncthreads();
            s[tid] += add;
            __syncthreads();
        }
        if (tid == 0) {
            int acc = 0;
            for (int tt = 0; tt < NT; ++tt) {
                pb[tt] = acc;
                int tot = s[(tt + 1) * NBLK_SCAN - 1] - (tt ? s[tt * NBLK_SCAN - 1] : 0);
                acc += ((tot + 15) >> 4) << 4;
            }
            pb[NT] = acc;
        }
        __syncthreads();
        if (tid < NT * NBLK_SCAN) {
            int excl = s[tid] - v;
            int base_t = t ? s[t * NBLK_SCAN - 1] : 0;
            bbase[b * NT + t] = pb[t] + (excl - base_t);
        }
        if (tid <= NT) pb_g[tid] = pb[tid];
        return;
    }
    // ---- scan1: block-local exclusive scan of edge counts (1024 elems/block) ----
    int sb = blockIdx.x - 1;
    __shared__ int s[1024];
    int i = sb * 1024 + tid;
    int v = (i < N_NODES) ? cnt[i] : 0;
    s[tid] = v;
    __syncthreads();
    for (int d = 1; d < 1024; d <<= 1) {
        int add = (tid >= d) ? s[tid - d] : 0;
        __syncthreads();
        s[tid] += add;
        __syncthreads();
    }
    if (i < N_NODES) offs[i] = s[tid] - v;
    if (tid == 1023) bsum[sb] = s[1023];
}

// ============ C: scatter (blocks 0..195) | scan2 (block 196) ============
__global__ __launch_bounds__(256) void k_C(
    const int* __restrict__ ntype, const int* __restrict__ bbase, int* __restrict__ order_pad,
    const int* __restrict__ bsum, int* __restrict__ bofs, int* __restrict__ offs)
{
    int blk = blockIdx.x;
    if (blk < NBLK_SCAN) {
        __shared__ int cur[NT];
        if (threadIdx.x < NT) cur[threadIdx.x] = bbase[blk * NT + threadIdx.x];
        __syncthreads();
        int n = blk * 256 + threadIdx.x;
        if (n < N_NODES) {
            int t = ntype[n];
            int pos = atomicAdd(&cur[t], 1);   // LDS atomic
            order_pad[pos] = n;
        }
        return;
    }
    // ---- scan2 over NBLK2 block sums; offs[N] pre-compensated for bofs ----
    __shared__ int s[256];
    int t = threadIdx.x;
    int v = (t < NBLK2) ? bsum[t] : 0;
    s[t] = v;
    __syncthreads();
    for (int d = 1; d < 256; d <<= 1) {
        int add = (t >= d) ? s[t - d] : 0;
        __syncthreads();
        s[t] += add;
        __syncthreads();
    }
    if (t < NBLK2) {
        int b = s[t] - v;
        bofs[t] = b;
        if (t == NBLK2 - 1) offs[N_NODES] = N_EDGES - b;  // so offs[N]+bofs[N>>10]==E
    }
}

// ============ D: MFMA projection (blocks < NTILE_ROW) | emit (rest) ============
// KVu layout per node: 64 groups x {k0,k1,v0,v1} ushorts (512B/row)
__global__ __launch_bounds__(256) void k_D(
    const unsigned short* __restrict__ xb, const unsigned short* __restrict__ Wt,
    const int* __restrict__ order_pad, const int* __restrict__ pb_g,
    const float* __restrict__ bq, const float* __restrict__ bk, const float* __restrict__ bv,
    float* __restrict__ Qf, unsigned short* __restrict__ KVu,
    const int* __restrict__ ei, const int* __restrict__ etype,
    const int* __restrict__ esign, const float* __restrict__ edist,
    const float* __restrict__ dalpha, const float* __restrict__ dtau,
    const int* __restrict__ offs, const int* __restrict__ bofs,
    const int* __restrict__ posw, int2* __restrict__ edata)
{
    int b = blockIdx.x;
    if (b >= NTILE_ROW) {
        // ---- emit edge records {src|cmb<<16, phi} into dst-sorted slots, no atomics ----
        int e = (b - NTILE_ROW) * 256 + threadIdx.x;
        if (e >= N_EDGES) return;
        int dst = ei[N_EDGES + e];
        int pos = offs[dst] + bofs[dst >> 10] + posw[e];
        int cmb = sign_index(esign[e]) * 8 + etype[e];
        float phi = dalpha[0] * __expf(-edist[e] / (dtau[0] + 1e-9f));
        edata[pos] = make_int2(ei[e] | (cmb << 16), __float_as_int(phi));
        return;
    }
    int row0 = b * 16;
    if (row0 >= pb_g[NT]) return;
    int t = (row0 >= pb_g[3]) ? 3 : (row0 >= pb_g[2]) ? 2 : (row0 >= pb_g[1]) ? 1 : 0;
    int wave = threadIdx.x >> 6, lane = threadIdx.x & 63;
    int arow = row0 + (lane & 15);
    int nidA = order_pad[arow];
    const unsigned short* xrow = xb + (size_t)(nidA < 0 ? 0 : nidA) * DIM;
    int ko = (lane >> 4) * 8;
    bf16x8 afrag[4];
    #pragma unroll
    for (int kt = 0; kt < 4; ++kt) afrag[kt] = *(const bf16x8*)(xrow + kt * 32 + ko);

    #pragma unroll
    for (int g = 0; g < 6; ++g) {
        int ocol = g * 64 + wave * 16 + (lane & 15);
        int sel = ocol >> 7, wcol = ocol & 127;
        const unsigned short* wrow = Wt + ((size_t)(t * 3 + sel) * DIM + wcol) * DIM;
        f32x4 acc = {0.f, 0.f, 0.f, 0.f};
        #pragma unroll
        for (int kt = 0; kt < 4; ++kt) {
            bf16x8 bfr = *(const bf16x8*)(wrow + kt * 32 + ko);
            acc = __builtin_amdgcn_mfma_f32_16x16x32_bf16(afrag[kt], bfr, acc, 0, 0, 0);
        }
        const float* bias_p = sel == 0 ? bq : (sel == 1 ? bk : bv);
        float bias = bias_p[t * DIM + wcol];
        #pragma unroll
        for (int r = 0; r < 4; ++r) {
            int drow = row0 + (lane >> 4) * 4 + r;
            int nid = order_pad[drow];
            if (nid < 0) continue;
            float v = acc[r] + bias;
            if (sel == 0) Qf[(size_t)nid * DIM + wcol] = v;
            else KVu[(size_t)nid * 256 + (wcol >> 1) * 4 + (wcol & 1) + (sel == 2 ? 2 : 0)] = f2bf(v);
        }
    }
}

// ============ E: fused attention + aggregation + skip + LN ============
// 256 threads = 4 waves; one wave per node. Each 32-lane HALF owns one edge;
// lane holds a 4-element quad. Score reduce = 2 width-4 shuffles.
__global__ __launch_bounds__(256) void k_attn(
    const float4* __restrict__ Qf4, const uint4* __restrict__ KV,
    const uint4* __restrict__ WCB,
    const float* __restrict__ x, const int* __restrict__ ntype,
    const int* __restrict__ offs, const int* __restrict__ bofs,
    const int2* __restrict__ edata,
    const float* __restrict__ rbias, const float* __restrict__ skip,
    const float* __restrict__ gmm, const float* __restrict__ bta,
    float* __restrict__ out)
{
    __shared__ float rb_s[NR * NH];
    if (threadIdx.x < NR * NH) rb_s[threadIdx.x] = rbias[threadIdx.x];
    __syncthreads();
    const int wave = threadIdx.x >> 6, lane = threadIdx.x & 63;
    const int n = blockIdx.x * 4 + wave;
    const int p = lane & 31;          // position quad index (elems 4p..4p+3)
    const int hi = lane >> 5;         // which edge of the pair this half owns
    const int h = p >> 2;             // head
    const int beg = offs[n] + bofs[n >> 10];
    const int end = offs[n + 1] + bofs[(n + 1) >> 10];

    const float4 q4 = Qf4[(size_t)n * 32 + p];

    float Z = 0.f, a0 = 0.f, a1 = 0.f, a2 = 0.f, a3 = 0.f;

    // scores bounded; exp without max-shift is safe in f32 (softmax shift-invariant)
    auto process = [&](int2 r) {
        int src = r.x & 0xffff;
        unsigned cmb = ((unsigned)r.x) >> 16;
        uint4 kv = KV[(size_t)src * 32 + p];
        uint4 w = WCB[cmb * 32 + p];
        float pp = (q4.x * blo(w.x)) * blo(kv.x);
        pp = fmaf(q4.y * bhi(w.x), bhi(kv.x), pp);
        pp = fmaf(q4.z * blo(w.z), blo(kv.z), pp);
        pp = fmaf(q4.w * bhi(w.z), bhi(kv.z), pp);
        pp += __shfl_xor(pp, 1, 4);
        pp += __shfl_xor(pp, 2, 4);
        float ex = __expf(pp + rb_s[(cmb & 7) * NH + h] + __int_as_float(r.y));
        Z += ex;
        a0 = fmaf(blo(kv.y) * blo(w.y), ex, a0);
        a1 = fmaf(bhi(kv.y) * bhi(w.y), ex, a1);
        a2 = fmaf(blo(kv.w) * blo(w.w), ex, a2);
        a3 = fmaf(bhi(kv.w) * bhi(w.w), ex, a3);
    };

    int rem = end - beg;
    int j = beg;
    if (rem >= 4) {
        // 2-pair (4-edge) unroll with 1-iter-ahead edata prefetch
        int2 r0 = edata[j + hi];
        int2 r1 = edata[j + 2 + hi];
        while (true) {
            int2 c0 = r0, c1 = r1;
            j += 4; rem -= 4;
            if (rem >= 4) { r0 = edata[j + hi]; r1 = edata[j + 2 + hi]; }
            process(c0);
            process(c1);
            if (rem < 4) break;
        }
    }
    while (rem >= 2) {
        int2 c = edata[j + hi];
        process(c);
        j += 2; rem -= 2;
    }
    if (rem) {
        // single leftover edge: both halves compute it; gate the hi half to zero
        int2 r = edata[j];
        int src = r.x & 0xffff;
        unsigned cmb = ((unsigned)r.x) >> 16;
        uint4 kv = KV[(size_t)src * 32 + p];
        uint4 w = WCB[cmb * 32 + p];
        float pp = (q4.x * blo(w.x)) * blo(kv.x);
        pp = fmaf(q4.y * bhi(w.x), bhi(kv.x), pp);
        pp = fmaf(q4.z * blo(w.z), blo(kv.z), pp);
        pp = fmaf(q4.w * bhi(w.z), bhi(kv.z), pp);
        pp += __shfl_xor(pp, 1, 4);
        pp += __shfl_xor(pp, 2, 4);
        float ex = __expf(pp + rb_s[(cmb & 7) * NH + h] + __int_as_float(r.y));
        ex = hi ? 0.f : ex;
        Z += ex;
        a0 = fmaf(blo(kv.y) * blo(w.y), ex, a0);
        a1 = fmaf(bhi(kv.y) * bhi(w.y), ex, a1);
        a2 = fmaf(blo(kv.w) * blo(w.w), ex, a2);
        a3 = fmaf(bhi(kv.w) * bhi(w.w), ex, a3);
    }

    // merge the two halves (lanes l and l+32 hold the same positions)
    Z  += __shfl_xor(Z, 32, 64);
    a0 += __shfl_xor(a0, 32, 64);
    a1 += __shfl_xor(a1, 32, 64);
    a2 += __shfl_xor(a2, 32, 64);
    a3 += __shfl_xor(a3, 32, 64);

    float rz = 1.f / (Z + 1e-9f);
    int t = ntype[n];
    float alpha = 1.f / (1.f + __expf(-skip[t]));
    float4 x4 = ((const float4*)x)[(size_t)n * 32 + p];
    float m0 = fmaf(alpha, a0 * rz - x4.x, x4.x);
    float m1 = fmaf(alpha, a1 * rz - x4.y, x4.y);
    float m2 = fmaf(alpha, a2 * rz - x4.z, x4.z);
    float m3 = fmaf(alpha, a3 * rz - x4.w, x4.w);

    float s = (m0 + m1) + (m2 + m3);
    float s2 = fmaf(m0, m0, m1 * m1) + fmaf(m2, m2, m3 * m3);
    #pragma unroll
    for (int d = 32; d >= 1; d >>= 1) {
        s += __shfl_xor(s, d, 64);
        s2 += __shfl_xor(s2, d, 64);
    }
    // both halves duplicated -> divide by 2*DIM
    float mu = s * (1.f / (2 * DIM));
    float var = s2 * (1.f / (2 * DIM)) - mu * mu;
    float rstd = rsqrtf(var + 1e-5f);
    if (hi == 0) {
        float4 g4 = ((const float4*)gmm)[t * 32 + p];
        float4 b4 = ((const float4*)bta)[t * 32 + p];
        float4 o4;
        o4.x = (m0 - mu) * rstd * g4.x + b4.x;
        o4.y = (m1 - mu) * rstd * g4.y + b4.y;
        o4.z = (m2 - mu) * rstd * g4.z + b4.z;
        o4.w = (m3 - mu) * rstd * g4.w + b4.w;
        ((float4*)out)[(size_t)n * 32 + p] = o4;
    }
}

extern "C" void kernel_launch(void* const* d_in, const int* in_sizes, int n_in,
                              void* d_out, int out_size, void* d_ws, size_t ws_size,
                              hipStream_t stream) {
    const float* x      = (const float*)d_in[0];
    const int*   ntype  = (const int*)d_in[1];
    const int*   ei     = (const int*)d_in[2];
    const int*   etype  = (const int*)d_in[3];
    const int*   esign  = (const int*)d_in[4];
    const float* edist  = (const float*)d_in[5];
    const float* Wq     = (const float*)d_in[6];
    const float* bq     = (const float*)d_in[7];
    const float* Wk     = (const float*)d_in[8];
    const float* bk     = (const float*)d_in[9];
    const float* Wv     = (const float*)d_in[10];
    const float* bv     = (const float*)d_in[11];
    const float* rel_q  = (const float*)d_in[12];
    const float* rel_k  = (const float*)d_in[13];
    const float* rel_v  = (const float*)d_in[14];
    const float* skn    = (const float*)d_in[15];
    const float* svn    = (const float*)d_in[16];
    const float* rbias  = (const float*)d_in[17];
    const float* dalpha = (const float*)d_in[18];
    const float* dtau   = (const float*)d_in[19];
    const float* skip   = (const float*)d_in[20];
    const float* gmm    = (const float*)d_in[21];
    const float* bta    = (const float*)d_in[22];
    float* out = (float*)d_out;

    char* ws = (char*)d_ws;
    float*          Qf     = (float*)         (ws + 0);          // 25.6 MB
    unsigned short* KVu    = (unsigned short*)(ws + 25600000);   // 25.6 MB interleaved K/V
    unsigned short* xb     = (unsigned short*)(ws + 51200000);   // 12.8 MB
    unsigned short* Wt     = (unsigned short*)(ws + 64000000);   // 393 KB
    uint4*          wcb    = (uint4*)         (ws + 64500000);   // 12.3 KB
    int*            cnt    = (int*)           (ws + 64600000);   // N
    int*            offs   = (int*)           (ws + 64900000);   // N+1
    int*            bsum   = (int*)           (ws + 65200000);   // 64
    int*            bofs   = (int*)           (ws + 65210000);   // 64
    int*            posw   = (int*)           (ws + 65300000);   // E = 3.2 MB
    int2*           edata  = (int2*)          (ws + 68600000);   // E*8 = 6.4 MB
    int*            opad   = (int*)           (ws + 75000000);   // NPAD_MAX
    int*            bhist  = (int*)           (ws + 75300000);   // 196*4
    int*            bbase  = (int*)           (ws + 75310000);   // 196*4
    int*            pb     = (int*)           (ws + 75320000);   // 5

    // 0. zero edge counters (must precede A's hist2 role)
    hipMemsetAsync(cnt, 0, (size_t)N_NODES * 4, stream);
    // A. typehist | prep | edge-histogram  (mutually independent)
    k_A <<<A_BLOCKS, 256, 0, stream>>>(ntype, bhist, opad,
                                       x, Wq, Wk, Wv, rel_q, rel_k, rel_v, skn, svn,
                                       xb, Wt, wcb, ei, cnt, posw);
    // B. typescan | scan1
    k_B <<<1 + NBLK2, 1024, 0, stream>>>(bhist, bbase, pb, cnt, offs, bsum);
    // C. scatter | scan2
    k_C <<<NBLK_SCAN + 1, 256, 0, stream>>>(ntype, bbase, opad, bsum, bofs, offs);
    // D. MFMA projection | emit  (independent big middles, co-resident)
    k_D <<<NTILE_ROW + HIST_BLOCKS, 256, 0, stream>>>(xb, Wt, opad, pb, bq, bk, bv,
                                                      Qf, KVu,
                                                      ei, etype, esign, edist, dalpha, dtau,
                                                      offs, bofs, posw, edata);
    // E. fused attention + aggregation + skip + LayerNorm
    k_attn <<<N_NODES / 4, 256, 0, stream>>>((const float4*)Qf, (const uint4*)KVu,
                                             (const uint4*)wcb, x, ntype, offs, bofs,
                                             edata, rbias, skip, gmm, bta, out);
}